// Round 18
// baseline (223.991 us; speedup 1.0000x reference)
//
#include <hip/hip_runtime.h>
#include <math.h>

#define MIN_NORM 1e-15f
#define MAXN 0.996f

typedef __attribute__((ext_vector_type(8))) short bf16x8;
typedef __attribute__((ext_vector_type(16))) float f32x16;

union U8 { unsigned short s[8]; bf16x8 v; };

static __device__ __forceinline__ float wsum(float v) {
#pragma unroll
    for (int o = 32; o > 0; o >>= 1) v += __shfl_xor(v, o, 64);
    return v;
}
static __device__ __forceinline__ float artanh_f(float x) {
    const float lim = 1.0f - 1e-6f;
    x = fminf(fmaxf(x, -lim), lim);
    return 0.5f * (log1pf(x) - log1pf(-x));
}

// 3-way bf16 split: a ~= hi + lo + lolo, residual ~2^-25|a|
static __device__ __forceinline__ void split3(float a, unsigned short& h,
                                              unsigned short& l, unsigned short& ll) {
    unsigned u = __float_as_uint(a);
    unsigned hb = u & 0xFFFF0000u;
    float r1 = a - __uint_as_float(hb);          // exact
    unsigned u1 = __float_as_uint(r1);
    unsigned lb = u1 & 0xFFFF0000u;
    float r2 = r1 - __uint_as_float(lb);         // exact
    unsigned u2 = __float_as_uint(r2);
    unsigned t = u2 + 0x7FFFu + ((u2 >> 16) & 1u); // RNE
    h = (unsigned short)(hb >> 16);
    l = (unsigned short)(lb >> 16);
    ll = (unsigned short)(t >> 16);
}

// ---------------- W transpose + hyperbolic bias (fused) ----------------
__global__ void k_transW_hb(const float* __restrict__ W, float* __restrict__ Wt,
                            const float* __restrict__ b_stack, float* __restrict__ hb) {
    int l = blockIdx.y;
    int t = blockIdx.x * 256 + threadIdx.x;   // 16384 per layer
    int k = t >> 7, d = t & 127;
    Wt[l * 16384 + k * 128 + d] = W[l * 16384 + d * 128 + k];
    if (blockIdx.x == 0 && threadIdx.x < 64) {
        int lane = threadIdx.x;
        float2 b = ((const float2*)(b_stack + l * 128))[lane];
        float n = fmaxf(sqrtf(wsum(b.x * b.x + b.y * b.y)), MIN_NORM);
        float sc = tanhf(n) / n;
        float hx = sc * b.x, hy = sc * b.y;
        float nm = fmaxf(sqrtf(wsum(hx * hx + hy * hy)), MIN_NORM);
        if (nm > MAXN) { float s = MAXN / nm; hx *= s; hy *= s; }
        ((float2*)(hb + l * 128))[lane] = make_float2(hx, hy);
    }
}

// ---------------- degree -> dinv = (rowsum + 10)^-1/2 ----------------
__global__ __launch_bounds__(256) void k_deg(const float* __restrict__ adj1,
                                             const float* __restrict__ adj2,
                                             float* __restrict__ dinv) {
    int row = blockIdx.x, g = blockIdx.y;
    const float* adj = (g ? adj2 : adj1) + (size_t)row * 4096;
    float s = 0.f;
    for (int i = threadIdx.x; i < 1024; i += 256) {
        float4 v = ((const float4*)adj)[i];
        s += v.x + v.y + v.z + v.w;
    }
    s = wsum(s);
    __shared__ float ls[4];
    if ((threadIdx.x & 63) == 0) ls[threadIdx.x >> 6] = s;
    __syncthreads();
    if (threadIdx.x == 0) {
        float t = ls[0] + ls[1] + ls[2] + ls[3] + 10.0f;
        dinv[g * 4096 + row] = (t > 0.f) ? (1.0f / sqrtf(t)) : 0.f;
    }
}

// ---------------- h0 = proj(expmap0(x)) ----------------
__global__ __launch_bounds__(256) void k_manifold(const float* __restrict__ x1,
                                                  const float* __restrict__ x2,
                                                  float* __restrict__ h) {
    int wid = threadIdx.x >> 6, lane = threadIdx.x & 63;
    int row = blockIdx.x * 4 + wid;          // 0..8191
    const float* x = (row < 4096 ? x1 : x2 - (size_t)4096 * 128) + (size_t)row * 128;
    float2 v = ((const float2*)x)[lane];
    float n = fmaxf(sqrtf(wsum(v.x * v.x + v.y * v.y)), MIN_NORM);
    float sc = tanhf(n) / n;
    float hx = sc * v.x, hy = sc * v.y;
    float nm = fmaxf(sqrtf(wsum(hx * hx + hy * hy)), MIN_NORM);
    if (nm > MAXN) { float s = MAXN / nm; hx *= s; hy *= s; }
    ((float2*)(h + (size_t)row * 128))[lane] = make_float2(hx, hy);
}

// ---------------- mx = h @ W.T  (A: 8192x128, Bt: 128x128 = W.T) ----------------
__global__ __launch_bounds__(256) void k_lin(const float* __restrict__ A,
                                             const float* __restrict__ Bt,
                                             float* __restrict__ C) {
    int r0 = blockIdx.x * 64;
    __shared__ float As[32][64];
    __shared__ float Bs[32][128];
    int t = threadIdx.x;
    int tx = t & 15, ty = t >> 4;
    float acc[4][8] = {};
    int ar = t >> 3;
    int ac = (t & 7) * 4;
    for (int kt = 0; kt < 128; kt += 32) {
        const float* Ap = A + (size_t)(r0 + ar) * 128 + kt + ac;
        float4 v0 = *(const float4*)Ap;
        float4 v1 = *(const float4*)(Ap + 32 * 128);
        As[ac + 0][ar] = v0.x; As[ac + 1][ar] = v0.y; As[ac + 2][ar] = v0.z; As[ac + 3][ar] = v0.w;
        As[ac + 0][ar + 32] = v1.x; As[ac + 1][ar + 32] = v1.y; As[ac + 2][ar + 32] = v1.z; As[ac + 3][ar + 32] = v1.w;
#pragma unroll
        for (int i = 0; i < 4; i++) {
            int f = t + 256 * i;
            int kr = f >> 5, c = (f & 31) * 4;
            *(float4*)&Bs[kr][c] = *(const float4*)(Bt + (size_t)(kt + kr) * 128 + c);
        }
        __syncthreads();
#pragma unroll
        for (int k = 0; k < 32; k++) {
            float4 a = *(const float4*)&As[k][ty * 4];
            float4 b0 = *(const float4*)&Bs[k][tx * 4];
            float4 b1 = *(const float4*)&Bs[k][64 + tx * 4];
            float av[4] = {a.x, a.y, a.z, a.w};
            float bv[8] = {b0.x, b0.y, b0.z, b0.w, b1.x, b1.y, b1.z, b1.w};
#pragma unroll
            for (int i = 0; i < 4; i++)
#pragma unroll
                for (int j = 0; j < 8; j++)
                    acc[i][j] = fmaf(av[i], bv[j], acc[i][j]);
        }
        __syncthreads();
    }
#pragma unroll
    for (int i = 0; i < 4; i++) {
        float* Cr = C + (size_t)(r0 + ty * 4 + i) * 128;
        *(float4*)(Cr + tx * 4) = make_float4(acc[i][0], acc[i][1], acc[i][2], acc[i][3]);
        *(float4*)(Cr + 64 + tx * 4) = make_float4(acc[i][4], acc[i][5], acc[i][6], acc[i][7]);
    }
}

// ---------------- rowwise: matvec-norm + mobius bias add + logmap0, * dinv ----------------
__global__ __launch_bounds__(256) void k_postlin(const float* __restrict__ h,
                                                 const float* __restrict__ mx,
                                                 const float* __restrict__ hb,
                                                 const float* __restrict__ dinv,
                                                 float* __restrict__ tp) {
    int wid = threadIdx.x >> 6, lane = threadIdx.x & 63;
    int row = blockIdx.x * 4 + wid;   // 0..8191
    float2 hv = ((const float2*)(h + (size_t)row * 128))[lane];
    float2 mv = ((const float2*)(mx + (size_t)row * 128))[lane];
    float xn = fmaxf(sqrtf(wsum(hv.x * hv.x + hv.y * hv.y)), MIN_NORM);
    float mxn = fmaxf(sqrtf(wsum(mv.x * mv.x + mv.y * mv.y)), MIN_NORM);
    float arg = mxn / xn * artanh_f(xn);
    float sc = tanhf(arg) / mxn;
    float rx = sc * mv.x, ry = sc * mv.y;
    float nr = fmaxf(sqrtf(wsum(rx * rx + ry * ry)), MIN_NORM);
    if (nr > MAXN) { float s = MAXN / nr; rx *= s; ry *= s; }
    float2 bv = ((const float2*)hb)[lane];
    float x2 = wsum(rx * rx + ry * ry);
    float y2 = wsum(bv.x * bv.x + bv.y * bv.y);
    float xy = wsum(rx * bv.x + ry * bv.y);
    float cx = 1.0f + 2.0f * xy + y2;
    float cy = 1.0f - x2;
    float den = fmaxf(1.0f + 2.0f * xy + x2 * y2, MIN_NORM);
    float mxo = (cx * rx + cy * bv.x) / den;
    float myo = (cx * ry + cy * bv.y) / den;
    float nm = fmaxf(sqrtf(wsum(mxo * mxo + myo * myo)), MIN_NORM);
    if (nm > MAXN) { float s = MAXN / nm; mxo *= s; myo *= s; }
    float nm2 = fmaxf(sqrtf(wsum(mxo * mxo + myo * myo)), MIN_NORM);
    float lsc = artanh_f(nm2) / nm2;
    float dv = dinv[row];
    ((float2*)(tp + (size_t)row * 128))[lane] =
        make_float2(dv * (lsc * mxo), dv * (lsc * myo));
}

// ---- tp [4096][128] fp32 -> packed MFMA B-fragments, hi/lo/lolo bf16 ----
__global__ __launch_bounds__(256) void k_tsplit(const float* __restrict__ tp,
                                                unsigned short* __restrict__ Ph,
                                                unsigned short* __restrict__ Pl,
                                                unsigned short* __restrict__ Pll) {
    __shared__ float L[64][128];
    int g = blockIdx.y;
    int k0 = blockIdx.x * 64;                  // 4 kb-blocks of 16
    const float* T = tp + ((size_t)g * 4096 + k0) * 128;
    int t = threadIdx.x;
#pragma unroll
    for (int i = 0; i < 8; i++) {
        int f = t + 256 * i;                   // float4 index
        int r = f >> 5, c4 = f & 31;
        *(float4*)&L[r][c4 * 4] = *(const float4*)(T + (size_t)r * 128 + c4 * 4);
    }
    __syncthreads();
    int c = t & 127, lhi = t >> 7;             // lhi in {0,1}
    int c31 = c & 31, ct = c >> 5;
#pragma unroll
    for (int q = 0; q < 4; q++) {
        int kb = (k0 >> 4) + q;
        U8 ah, al, al2;
#pragma unroll
        for (int j = 0; j < 8; j++)
            split3(L[q * 16 + lhi * 8 + j][c], ah.s[j], al.s[j], al2.s[j]);
        size_t off = ((((size_t)g * 256 + kb) * 4 + ct) * 64 + lhi * 32 + c31) * 8;
        *(bf16x8*)(Ph + off) = ah.v;
        *(bf16x8*)(Pl + off) = al.v;
        *(bf16x8*)(Pll + off) = al2.v;
    }
}

// ---- one MFMA k-step for TWO 32-row tiles sharing the same 12 B chunks ----
static __device__ __forceinline__ void step16x2(const unsigned short Bsc[][512], int cb,
                                                int lane, float4 a0, float4 a1,
                                                float4 c0, float4 c1,
                                                f32x16* accA, f32x16* accB) {
    bf16x8 bh[4], bl[4], bll[4];
#pragma unroll
    for (int ct = 0; ct < 4; ct++) {
        bh[ct]  = *(const bf16x8*)&Bsc[cb + ct][lane * 8];
        bl[ct]  = *(const bf16x8*)&Bsc[cb + 4 + ct][lane * 8];
        bll[ct] = *(const bf16x8*)&Bsc[cb + 8 + ct][lane * 8];
    }
    U8 xh, xl, xq, yh, yl, yq;
    float xa[8] = {a0.x, a0.y, a0.z, a0.w, a1.x, a1.y, a1.z, a1.w};
    float ya[8] = {c0.x, c0.y, c0.z, c0.w, c1.x, c1.y, c1.z, c1.w};
#pragma unroll
    for (int j = 0; j < 8; j++) { split3(xa[j], xh.s[j], xl.s[j], xq.s[j]);
                                  split3(ya[j], yh.s[j], yl.s[j], yq.s[j]); }
#pragma unroll
    for (int ct = 0; ct < 4; ct++) {
        accA[ct] = __builtin_amdgcn_mfma_f32_32x32x16_bf16(xh.v, bh[ct], accA[ct], 0, 0, 0);
        accB[ct] = __builtin_amdgcn_mfma_f32_32x32x16_bf16(yh.v, bh[ct], accB[ct], 0, 0, 0);
    }
#pragma unroll
    for (int ct = 0; ct < 4; ct++) {
        accA[ct] = __builtin_amdgcn_mfma_f32_32x32x16_bf16(xl.v, bh[ct], accA[ct], 0, 0, 0);
        accB[ct] = __builtin_amdgcn_mfma_f32_32x32x16_bf16(yl.v, bh[ct], accB[ct], 0, 0, 0);
    }
#pragma unroll
    for (int ct = 0; ct < 4; ct++) {
        accA[ct] = __builtin_amdgcn_mfma_f32_32x32x16_bf16(xh.v, bl[ct], accA[ct], 0, 0, 0);
        accB[ct] = __builtin_amdgcn_mfma_f32_32x32x16_bf16(yh.v, bl[ct], accB[ct], 0, 0, 0);
    }
#pragma unroll
    for (int ct = 0; ct < 4; ct++) {
        accA[ct] = __builtin_amdgcn_mfma_f32_32x32x16_bf16(xl.v, bl[ct], accA[ct], 0, 0, 0);
        accB[ct] = __builtin_amdgcn_mfma_f32_32x32x16_bf16(yl.v, bl[ct], accB[ct], 0, 0, 0);
    }
#pragma unroll
    for (int ct = 0; ct < 4; ct++) {
        accA[ct] = __builtin_amdgcn_mfma_f32_32x32x16_bf16(xh.v, bll[ct], accA[ct], 0, 0, 0);
        accB[ct] = __builtin_amdgcn_mfma_f32_32x32x16_bf16(yh.v, bll[ct], accB[ct], 0, 0, 0);
    }
#pragma unroll
    for (int ct = 0; ct < 4; ct++) {
        accA[ct] = __builtin_amdgcn_mfma_f32_32x32x16_bf16(xq.v, bh[ct], accA[ct], 0, 0, 0);
        accB[ct] = __builtin_amdgcn_mfma_f32_32x32x16_bf16(yq.v, bh[ct], accB[ct], 0, 0, 0);
    }
}

// ---------------- k_agg: 64 rows/wave (2 tiles), LDS B traffic per row HALVED --------
// grid (16 mtiles, 8 kslices, 2 graphs), 256 thr = 4 waves, block = 256 rows x 128 cols
__global__ __launch_bounds__(256, 1) void k_agg_mfma(
    const float* __restrict__ adj1, const float* __restrict__ adj2,
    const unsigned short* __restrict__ Ph, const unsigned short* __restrict__ Pl,
    const unsigned short* __restrict__ Pll, float* __restrict__ part) {
    // 2 buffers x 24 chunks (12 per k-step x 2 steps) x 1KB
    __shared__ __align__(16) unsigned short Bs[2][24][512];
    const int w = threadIdx.x >> 6, lane = threadIdx.x & 63;
    const int mt = blockIdx.x, ks = blockIdx.y, g = blockIdx.z;
    const float* __restrict__ A = g ? adj2 : adj1;
    const int l31 = lane & 31, lhi = lane >> 5;
    const float* Ap0 = A + (size_t)(mt * 256 + w * 32 + l31) * 4096 + ks * 512 + lhi * 8;
    const float* Ap1 = Ap0 + (size_t)128 * 4096;

    // this wave stages chunks c = 6w .. 6w+5 (covering both k-steps of a pair)
    const unsigned short* src[6];
#pragma unroll
    for (int i = 0; i < 6; i++) {
        int c = w * 6 + i;
        int step = (c >= 12) ? 1 : 0;
        int cc = c - step * 12;
        const unsigned short* Pb = (cc < 4) ? Ph : ((cc < 8) ? Pl : Pll);
        src[i] = Pb + ((((size_t)(g * 256 + ks * 32 + step)) * 4 + (cc & 3)) * 64 + lane) * 8;
    }

    f32x16 accA[4] = {}, accB[4] = {};
    // A regs: 2 tiles x 2 k-steps x 8 floats per lane (cur + next)
    float4 a0 = *(const float4*)Ap0,        a1 = *(const float4*)(Ap0 + 4);
    float4 a2 = *(const float4*)(Ap0 + 16), a3 = *(const float4*)(Ap0 + 20);
    float4 a4 = *(const float4*)Ap1,        a5 = *(const float4*)(Ap1 + 4);
    float4 a6 = *(const float4*)(Ap1 + 16), a7 = *(const float4*)(Ap1 + 20);

    // prologue: stage pair 0 into buffer 0
    {
        bf16x8 r0 = *(const bf16x8*)(src[0]);
        bf16x8 r1 = *(const bf16x8*)(src[1]);
        bf16x8 r2 = *(const bf16x8*)(src[2]);
        bf16x8 r3 = *(const bf16x8*)(src[3]);
        bf16x8 r4 = *(const bf16x8*)(src[4]);
        bf16x8 r5 = *(const bf16x8*)(src[5]);
        *(bf16x8*)&Bs[0][w * 6 + 0][lane * 8] = r0;
        *(bf16x8*)&Bs[0][w * 6 + 1][lane * 8] = r1;
        *(bf16x8*)&Bs[0][w * 6 + 2][lane * 8] = r2;
        *(bf16x8*)&Bs[0][w * 6 + 3][lane * 8] = r3;
        *(bf16x8*)&Bs[0][w * 6 + 4][lane * 8] = r4;
        *(bf16x8*)&Bs[0][w * 6 + 5][lane * 8] = r5;
    }
    __syncthreads();

    for (int p = 0; p < 16; p++) {
        const int cur = p & 1;
        const bool more = (p + 1 < 16);
        // 1. issue staged B loads for pair p+1
        bf16x8 r0, r1, r2, r3, r4, r5;
        if (more) {
            size_t adv = (size_t)(p + 1) * 4096;
            r0 = *(const bf16x8*)(src[0] + adv);
            r1 = *(const bf16x8*)(src[1] + adv);
            r2 = *(const bf16x8*)(src[2] + adv);
            r3 = *(const bf16x8*)(src[3] + adv);
            r4 = *(const bf16x8*)(src[4] + adv);
            r5 = *(const bf16x8*)(src[5] + adv);
        }
        // A prefetch for next pair (crosses the raw barrier)
        const float* An0 = more ? (Ap0 + 32) : Ap0;
        const float* An1 = more ? (Ap1 + 32) : Ap1;
        float4 n0 = *(const float4*)An0,        n1 = *(const float4*)(An0 + 4);
        float4 n2 = *(const float4*)(An0 + 16), n3 = *(const float4*)(An0 + 20);
        float4 n4 = *(const float4*)An1,        n5 = *(const float4*)(An1 + 4);
        float4 n6 = *(const float4*)(An1 + 16), n7 = *(const float4*)(An1 + 20);
        Ap0 += 32; Ap1 += 32;
        // 2+3. compute both k-steps of this pair, both row tiles
        step16x2(Bs[cur], 0,  lane, a0, a1, a4, a5, accA, accB);
        step16x2(Bs[cur], 12, lane, a2, a3, a6, a7, accA, accB);
        // 4. write staged regs into the other buffer
        if (more) {
            const int nb = cur ^ 1;
            *(bf16x8*)&Bs[nb][w * 6 + 0][lane * 8] = r0;
            *(bf16x8*)&Bs[nb][w * 6 + 1][lane * 8] = r1;
            *(bf16x8*)&Bs[nb][w * 6 + 2][lane * 8] = r2;
            *(bf16x8*)&Bs[nb][w * 6 + 3][lane * 8] = r3;
            *(bf16x8*)&Bs[nb][w * 6 + 4][lane * 8] = r4;
            *(bf16x8*)&Bs[nb][w * 6 + 5][lane * 8] = r5;
        }
        // RAW barrier: lgkmcnt(0) publishes ds_writes; vmcnt NOT drained.
        asm volatile("s_waitcnt lgkmcnt(0)" ::: "memory");
        __builtin_amdgcn_sched_barrier(0);
        __builtin_amdgcn_s_barrier();
        a0 = n0; a1 = n1; a2 = n2; a3 = n3;
        a4 = n4; a5 = n5; a6 = n6; a7 = n7;
    }

    float* P = part + ((size_t)(g * 8 + ks) * 4096) * 128;
    const int rb0 = mt * 256 + w * 32 + 4 * lhi;
#pragma unroll
    for (int ct = 0; ct < 4; ct++) {
        const int c = ct * 32 + l31;
#pragma unroll
        for (int q = 0; q < 16; q++) {
            int dr = (q & 3) + 8 * (q >> 2);
            P[(size_t)(rb0 + dr) * 128 + c] = accA[ct][q];
            P[(size_t)(rb0 + 128 + dr) * 128 + c] = accB[ct][q];
        }
    }
}

// ---------------- reduce partials + self-loop + dinv, then postagg chain -> h ----------
__global__ __launch_bounds__(256) void k_reduce(const float* __restrict__ part,
                                                const float* __restrict__ tp,
                                                const float* __restrict__ dinv,
                                                float* __restrict__ h) {
    int wid = threadIdx.x >> 6, lane = threadIdx.x & 63;
    int row = blockIdx.x * 4 + wid;          // 0..8191
    int g = row >> 12, rr = row & 4095;
    float sx = 0.f, sy = 0.f;
    const float* P = part + ((size_t)(g * 8) * 4096 + rr) * 128;
#pragma unroll
    for (int ks = 0; ks < 8; ks++) {
        float2 v = ((const float2*)(P + (size_t)ks * 4096 * 128))[lane];
        sx += v.x; sy += v.y;
    }
    float2 tv = ((const float2*)(tp + (size_t)row * 128))[lane];
    float d = dinv[row];
    float vx = d * (sx + 10.0f * tv.x);
    float vy = d * (sy + 10.0f * tv.y);
    float n = fmaxf(sqrtf(wsum(vx * vx + vy * vy)), MIN_NORM);
    float e = tanhf(n) / n;
    float px = e * vx, py = e * vy;
    float nm = fmaxf(sqrtf(wsum(px * px + py * py)), MIN_NORM);
    if (nm > MAXN) { float s = MAXN / nm; px *= s; py *= s; }
    float nm2 = fmaxf(sqrtf(wsum(px * px + py * py)), MIN_NORM);
    float lsc = artanh_f(nm2) / nm2;
    float tx2 = fmaxf(lsc * px, 0.0f), ty2 = fmaxf(lsc * py, 0.0f);
    float nr = fmaxf(sqrtf(wsum(tx2 * tx2 + ty2 * ty2)), MIN_NORM);
    float e2 = tanhf(nr) / nr;
    float hx = e2 * tx2, hy = e2 * ty2;
    float nh = fmaxf(sqrtf(wsum(hx * hx + hy * hy)), MIN_NORM);
    if (nh > MAXN) { float s = MAXN / nh; hx *= s; hy *= s; }
    ((float2*)(h + (size_t)row * 128))[lane] = make_float2(hx, hy);
}

// ---------------- readout partials: per 128-row chunk, per column sum & max ----------------
__global__ __launch_bounds__(256) void k_red_part(const float* __restrict__ h,
                                                  float* __restrict__ part) {
    int chunk = blockIdx.x;                // 64 chunks x 128 rows
    int col = threadIdx.x & 127, half = threadIdx.x >> 7;
    float s = 0.f, m = -INFINITY;
    for (int i = 0; i < 64; i++) {
        int r = chunk * 128 + half * 64 + i;
        float v = h[(size_t)r * 128 + col];
        s += v;
        m = fmaxf(m, v);
    }
    __shared__ float ss[128], sm[128];
    if (half) { ss[col] = s; sm[col] = m; }
    __syncthreads();
    if (!half) {
        s += ss[col];
        m = fmaxf(m, sm[col]);
        part[(chunk * 2 + 0) * 128 + col] = s;
        part[(chunk * 2 + 1) * 128 + col] = m;
    }
}

__global__ void k_red_final(const float* __restrict__ part, float* __restrict__ feat) {
    int g = blockIdx.x, col = threadIdx.x;   // 128 threads
    float s = 0.f, m = -INFINITY;
    for (int c = g * 32; c < g * 32 + 32; c++) {
        s += part[(c * 2 + 0) * 128 + col];
        m = fmaxf(m, part[(c * 2 + 1) * 128 + col]);
    }
    feat[g * 256 + col] = s * (1.0f / 4096.0f);
    feat[g * 256 + 128 + col] = m;
}

// ---------------- MLP (128 blocks: one output neuron per block) ----------------
__global__ __launch_bounds__(256) void k_mlp_hidden(const float* __restrict__ feat,
                                                    const float* __restrict__ W1,
                                                    const float* __restrict__ b1,
                                                    float* __restrict__ hidden) {
    int j = blockIdx.x;      // 128
    int t = threadIdx.x;     // 256
    float p = 0.f;
    for (int k = t; k < 768; k += 256) {
        float f = (k < 512) ? feat[k] : (feat[k - 512] - feat[k - 256]);
        p = fmaf(f, W1[j * 768 + k], p);
    }
    p = wsum(p);
    __shared__ float ps[4];
    if ((t & 63) == 0) ps[t >> 6] = p;
    __syncthreads();
    if (t == 0) {
        float x = ps[0] + ps[1] + ps[2] + ps[3] + b1[j];
        hidden[j] = 0.5f * x * (1.0f + erff(x * 0.70710678118654752f));
    }
}

__global__ void k_mlp_out(const float* __restrict__ hidden, const float* __restrict__ W2,
                          const float* __restrict__ b2, float* __restrict__ out) {
    int t = threadIdx.x;   // 128
    float v = hidden[t] * W2[t];
    v = wsum(v);
    __shared__ float ps[2];
    if ((t & 63) == 0) ps[t >> 6] = v;
    __syncthreads();
    if (t == 0) out[0] = ps[0] + ps[1] + b2[0];
}

extern "C" void kernel_launch(void* const* d_in, const int* in_sizes, int n_in,
                              void* d_out, int out_size, void* d_ws, size_t ws_size,
                              hipStream_t stream) {
    (void)in_sizes; (void)n_in; (void)out_size; (void)ws_size;
    const float* x1 = (const float*)d_in[0];
    const float* x2 = (const float*)d_in[1];
    const float* adj1 = (const float*)d_in[2];
    const float* adj2 = (const float*)d_in[3];
    const float* W_stack = (const float*)d_in[6];
    const float* b_stack = (const float*)d_in[7];
    const float* W1 = (const float*)d_in[8];
    const float* b1 = (const float*)d_in[9];
    const float* W2 = (const float*)d_in[10];
    const float* b2 = (const float*)d_in[11];

    float* ws = (float*)d_ws;
    float* dinv = ws;                        // 8192
    float* hb   = ws + 8192;                 // 256
    float* Wt   = ws + 8448;                 // 32768
    float* h    = ws + 41216;                // 1048576
    float* mx   = h + 1048576;               // 1048576
    float* tp   = mx + 1048576;              // 1048576
    float* part = tp + 1048576;              // 2*8*4096*128 = 8388608
    float* rpart = part + 8388608;           // 16384
    float* feat = rpart + 16384;             // 512
    float* hid  = feat + 512;                // 128
    unsigned short* Ph  = (unsigned short*)(hid + 128);   // 2*128*4096 each
    unsigned short* Pl  = Ph + 2 * 128 * 4096;
    unsigned short* Pll = Pl + 2 * 128 * 4096;

    k_transW_hb<<<dim3(64, 2), 256, 0, stream>>>(W_stack, Wt, b_stack, hb);
    k_deg<<<dim3(4096, 2), 256, 0, stream>>>(adj1, adj2, dinv);
    k_manifold<<<2048, 256, 0, stream>>>(x1, x2, h);
    for (int l = 0; l < 2; l++) {
        k_lin<<<128, 256, 0, stream>>>(h, Wt + l * 16384, mx);
        k_postlin<<<2048, 256, 0, stream>>>(h, mx, hb + l * 128, dinv, tp);
        k_tsplit<<<dim3(64, 2), 256, 0, stream>>>(tp, Ph, Pl, Pll);
        k_agg_mfma<<<dim3(16, 8, 2), 256, 0, stream>>>(adj1, adj2, Ph, Pl, Pll, part);
        k_reduce<<<2048, 256, 0, stream>>>(part, tp, dinv, h);
    }
    k_red_part<<<64, 256, 0, stream>>>(h, rpart);
    k_red_final<<<2, 128, 0, stream>>>(rpart, feat);
    k_mlp_hidden<<<128, 256, 0, stream>>>(feat, W1, b1, hid);
    k_mlp_out<<<1, 128, 0, stream>>>(hid, W2, b2, (float*)d_out);
}

// Round 19
// 211.947 us; speedup vs baseline: 1.0568x; 1.0568x over previous
//
#include <hip/hip_runtime.h>
#include <math.h>

#define MIN_NORM 1e-15f
#define MAXN 0.996f

typedef __attribute__((ext_vector_type(8))) short bf16x8;
typedef __attribute__((ext_vector_type(16))) float f32x16;

union U8 { unsigned short s[8]; bf16x8 v; };

static __device__ __forceinline__ float wsum(float v) {
#pragma unroll
    for (int o = 32; o > 0; o >>= 1) v += __shfl_xor(v, o, 64);
    return v;
}
static __device__ __forceinline__ float artanh_f(float x) {
    const float lim = 1.0f - 1e-6f;
    x = fminf(fmaxf(x, -lim), lim);
    return 0.5f * (log1pf(x) - log1pf(-x));
}

// 3-way bf16 split: a ~= hi + lo + lolo, residual ~2^-25|a|
static __device__ __forceinline__ void split3(float a, unsigned short& h,
                                              unsigned short& l, unsigned short& ll) {
    unsigned u = __float_as_uint(a);
    unsigned hb = u & 0xFFFF0000u;
    float r1 = a - __uint_as_float(hb);          // exact
    unsigned u1 = __float_as_uint(r1);
    unsigned lb = u1 & 0xFFFF0000u;
    float r2 = r1 - __uint_as_float(lb);         // exact
    unsigned u2 = __float_as_uint(r2);
    unsigned t = u2 + 0x7FFFu + ((u2 >> 16) & 1u); // RNE
    h = (unsigned short)(hb >> 16);
    l = (unsigned short)(lb >> 16);
    ll = (unsigned short)(t >> 16);
}

// ---------------- W transpose + hyperbolic bias (fused) ----------------
__global__ void k_transW_hb(const float* __restrict__ W, float* __restrict__ Wt,
                            const float* __restrict__ b_stack, float* __restrict__ hb) {
    int l = blockIdx.y;
    int t = blockIdx.x * 256 + threadIdx.x;   // 16384 per layer
    int k = t >> 7, d = t & 127;
    Wt[l * 16384 + k * 128 + d] = W[l * 16384 + d * 128 + k];
    if (blockIdx.x == 0 && threadIdx.x < 64) {
        int lane = threadIdx.x;
        float2 b = ((const float2*)(b_stack + l * 128))[lane];
        float n = fmaxf(sqrtf(wsum(b.x * b.x + b.y * b.y)), MIN_NORM);
        float sc = tanhf(n) / n;
        float hx = sc * b.x, hy = sc * b.y;
        float nm = fmaxf(sqrtf(wsum(hx * hx + hy * hy)), MIN_NORM);
        if (nm > MAXN) { float s = MAXN / nm; hx *= s; hy *= s; }
        ((float2*)(hb + l * 128))[lane] = make_float2(hx, hy);
    }
}

// ---------------- degree -> dinv = (rowsum + 10)^-1/2 ----------------
__global__ __launch_bounds__(256) void k_deg(const float* __restrict__ adj1,
                                             const float* __restrict__ adj2,
                                             float* __restrict__ dinv) {
    int row = blockIdx.x, g = blockIdx.y;
    const float* adj = (g ? adj2 : adj1) + (size_t)row * 4096;
    float s = 0.f;
    for (int i = threadIdx.x; i < 1024; i += 256) {
        float4 v = ((const float4*)adj)[i];
        s += v.x + v.y + v.z + v.w;
    }
    s = wsum(s);
    __shared__ float ls[4];
    if ((threadIdx.x & 63) == 0) ls[threadIdx.x >> 6] = s;
    __syncthreads();
    if (threadIdx.x == 0) {
        float t = ls[0] + ls[1] + ls[2] + ls[3] + 10.0f;
        dinv[g * 4096 + row] = (t > 0.f) ? (1.0f / sqrtf(t)) : 0.f;
    }
}

// ---------------- h0 = proj(expmap0(x)) ----------------
__global__ __launch_bounds__(256) void k_manifold(const float* __restrict__ x1,
                                                  const float* __restrict__ x2,
                                                  float* __restrict__ h) {
    int wid = threadIdx.x >> 6, lane = threadIdx.x & 63;
    int row = blockIdx.x * 4 + wid;          // 0..8191
    const float* x = (row < 4096 ? x1 : x2 - (size_t)4096 * 128) + (size_t)row * 128;
    float2 v = ((const float2*)x)[lane];
    float n = fmaxf(sqrtf(wsum(v.x * v.x + v.y * v.y)), MIN_NORM);
    float sc = tanhf(n) / n;
    float hx = sc * v.x, hy = sc * v.y;
    float nm = fmaxf(sqrtf(wsum(hx * hx + hy * hy)), MIN_NORM);
    if (nm > MAXN) { float s = MAXN / nm; hx *= s; hy *= s; }
    ((float2*)(h + (size_t)row * 128))[lane] = make_float2(hx, hy);
}

// ---------------- mx = h @ W.T  (A: 8192x128, Bt: 128x128 = W.T) ----------------
__global__ __launch_bounds__(256) void k_lin(const float* __restrict__ A,
                                             const float* __restrict__ Bt,
                                             float* __restrict__ C) {
    int r0 = blockIdx.x * 64;
    __shared__ float As[32][64];
    __shared__ float Bs[32][128];
    int t = threadIdx.x;
    int tx = t & 15, ty = t >> 4;
    float acc[4][8] = {};
    int ar = t >> 3;
    int ac = (t & 7) * 4;
    for (int kt = 0; kt < 128; kt += 32) {
        const float* Ap = A + (size_t)(r0 + ar) * 128 + kt + ac;
        float4 v0 = *(const float4*)Ap;
        float4 v1 = *(const float4*)(Ap + 32 * 128);
        As[ac + 0][ar] = v0.x; As[ac + 1][ar] = v0.y; As[ac + 2][ar] = v0.z; As[ac + 3][ar] = v0.w;
        As[ac + 0][ar + 32] = v1.x; As[ac + 1][ar + 32] = v1.y; As[ac + 2][ar + 32] = v1.z; As[ac + 3][ar + 32] = v1.w;
#pragma unroll
        for (int i = 0; i < 4; i++) {
            int f = t + 256 * i;
            int kr = f >> 5, c = (f & 31) * 4;
            *(float4*)&Bs[kr][c] = *(const float4*)(Bt + (size_t)(kt + kr) * 128 + c);
        }
        __syncthreads();
#pragma unroll
        for (int k = 0; k < 32; k++) {
            float4 a = *(const float4*)&As[k][ty * 4];
            float4 b0 = *(const float4*)&Bs[k][tx * 4];
            float4 b1 = *(const float4*)&Bs[k][64 + tx * 4];
            float av[4] = {a.x, a.y, a.z, a.w};
            float bv[8] = {b0.x, b0.y, b0.z, b0.w, b1.x, b1.y, b1.z, b1.w};
#pragma unroll
            for (int i = 0; i < 4; i++)
#pragma unroll
                for (int j = 0; j < 8; j++)
                    acc[i][j] = fmaf(av[i], bv[j], acc[i][j]);
        }
        __syncthreads();
    }
#pragma unroll
    for (int i = 0; i < 4; i++) {
        float* Cr = C + (size_t)(r0 + ty * 4 + i) * 128;
        *(float4*)(Cr + tx * 4) = make_float4(acc[i][0], acc[i][1], acc[i][2], acc[i][3]);
        *(float4*)(Cr + 64 + tx * 4) = make_float4(acc[i][4], acc[i][5], acc[i][6], acc[i][7]);
    }
}

// ---------------- rowwise: matvec-norm + mobius bias add + logmap0, * dinv ----------------
__global__ __launch_bounds__(256) void k_postlin(const float* __restrict__ h,
                                                 const float* __restrict__ mx,
                                                 const float* __restrict__ hb,
                                                 const float* __restrict__ dinv,
                                                 float* __restrict__ tp) {
    int wid = threadIdx.x >> 6, lane = threadIdx.x & 63;
    int row = blockIdx.x * 4 + wid;   // 0..8191
    float2 hv = ((const float2*)(h + (size_t)row * 128))[lane];
    float2 mv = ((const float2*)(mx + (size_t)row * 128))[lane];
    float xn = fmaxf(sqrtf(wsum(hv.x * hv.x + hv.y * hv.y)), MIN_NORM);
    float mxn = fmaxf(sqrtf(wsum(mv.x * mv.x + mv.y * mv.y)), MIN_NORM);
    float arg = mxn / xn * artanh_f(xn);
    float sc = tanhf(arg) / mxn;
    float rx = sc * mv.x, ry = sc * mv.y;
    float nr = fmaxf(sqrtf(wsum(rx * rx + ry * ry)), MIN_NORM);
    if (nr > MAXN) { float s = MAXN / nr; rx *= s; ry *= s; }
    float2 bv = ((const float2*)hb)[lane];
    float x2 = wsum(rx * rx + ry * ry);
    float y2 = wsum(bv.x * bv.x + bv.y * bv.y);
    float xy = wsum(rx * bv.x + ry * bv.y);
    float cx = 1.0f + 2.0f * xy + y2;
    float cy = 1.0f - x2;
    float den = fmaxf(1.0f + 2.0f * xy + x2 * y2, MIN_NORM);
    float mxo = (cx * rx + cy * bv.x) / den;
    float myo = (cx * ry + cy * bv.y) / den;
    float nm = fmaxf(sqrtf(wsum(mxo * mxo + myo * myo)), MIN_NORM);
    if (nm > MAXN) { float s = MAXN / nm; mxo *= s; myo *= s; }
    float nm2 = fmaxf(sqrtf(wsum(mxo * mxo + myo * myo)), MIN_NORM);
    float lsc = artanh_f(nm2) / nm2;
    float dv = dinv[row];
    ((float2*)(tp + (size_t)row * 128))[lane] =
        make_float2(dv * (lsc * mxo), dv * (lsc * myo));
}

// ---- tp [4096][128] fp32 -> packed MFMA B-fragments, hi/lo/lolo bf16 ----
// pack element (col c, k) at: ((((g*256+kb)*4 + ct)*64 + lhi*32 + c31)*8 + j)
__global__ __launch_bounds__(256) void k_tsplit(const float* __restrict__ tp,
                                                unsigned short* __restrict__ Ph,
                                                unsigned short* __restrict__ Pl,
                                                unsigned short* __restrict__ Pll) {
    __shared__ float L[64][128];
    int g = blockIdx.y;
    int k0 = blockIdx.x * 64;                  // 4 kb-blocks of 16
    const float* T = tp + ((size_t)g * 4096 + k0) * 128;
    int t = threadIdx.x;
#pragma unroll
    for (int i = 0; i < 8; i++) {
        int f = t + 256 * i;                   // float4 index
        int r = f >> 5, c4 = f & 31;
        *(float4*)&L[r][c4 * 4] = *(const float4*)(T + (size_t)r * 128 + c4 * 4);
    }
    __syncthreads();
    int c = t & 127, lhi = t >> 7;             // lhi in {0,1}
    int c31 = c & 31, ct = c >> 5;
#pragma unroll
    for (int q = 0; q < 4; q++) {
        int kb = (k0 >> 4) + q;
        U8 ah, al, al2;
#pragma unroll
        for (int j = 0; j < 8; j++)
            split3(L[q * 16 + lhi * 8 + j][c], ah.s[j], al.s[j], al2.s[j]);
        size_t off = ((((size_t)g * 256 + kb) * 4 + ct) * 64 + lhi * 32 + c31) * 8;
        *(bf16x8*)(Ph + off) = ah.v;
        *(bf16x8*)(Pl + off) = al.v;
        *(bf16x8*)(Pll + off) = al2.v;
    }
}

// ---------------- one MFMA k-step: 12 LDS chunk reads + split3(A) + 24 MFMAs ----------
static __device__ __forceinline__ void step16(const unsigned short Bsc[][512], int cb,
                                              int lane, float4 a0, float4 a1,
                                              f32x16* acc) {
    bf16x8 bh[4], bl[4], bll[4];
#pragma unroll
    for (int ct = 0; ct < 4; ct++) {
        bh[ct]  = *(const bf16x8*)&Bsc[cb + ct][lane * 8];
        bl[ct]  = *(const bf16x8*)&Bsc[cb + 4 + ct][lane * 8];
        bll[ct] = *(const bf16x8*)&Bsc[cb + 8 + ct][lane * 8];
    }
    U8 ah, al, al2;
    float av[8] = {a0.x, a0.y, a0.z, a0.w, a1.x, a1.y, a1.z, a1.w};
#pragma unroll
    for (int j = 0; j < 8; j++) split3(av[j], ah.s[j], al.s[j], al2.s[j]);
#pragma unroll
    for (int ct = 0; ct < 4; ct++)
        acc[ct] = __builtin_amdgcn_mfma_f32_32x32x16_bf16(ah.v, bh[ct], acc[ct], 0, 0, 0);
#pragma unroll
    for (int ct = 0; ct < 4; ct++)
        acc[ct] = __builtin_amdgcn_mfma_f32_32x32x16_bf16(al.v, bh[ct], acc[ct], 0, 0, 0);
#pragma unroll
    for (int ct = 0; ct < 4; ct++)
        acc[ct] = __builtin_amdgcn_mfma_f32_32x32x16_bf16(ah.v, bl[ct], acc[ct], 0, 0, 0);
#pragma unroll
    for (int ct = 0; ct < 4; ct++)
        acc[ct] = __builtin_amdgcn_mfma_f32_32x32x16_bf16(al.v, bl[ct], acc[ct], 0, 0, 0);
#pragma unroll
    for (int ct = 0; ct < 4; ct++)
        acc[ct] = __builtin_amdgcn_mfma_f32_32x32x16_bf16(ah.v, bll[ct], acc[ct], 0, 0, 0);
#pragma unroll
    for (int ct = 0; ct < 4; ct++)
        acc[ct] = __builtin_amdgcn_mfma_f32_32x32x16_bf16(al2.v, bh[ct], acc[ct], 0, 0, 0);
}

// ---------------- k_agg: LDS-staged B, 2 k-steps per barrier (16 barriers) ----------
// grid (32 mtiles, 8 kslices, 2 graphs), 256 thr = 4 waves, wave = 32 rows x 128 cols
__global__ __launch_bounds__(256, 2) void k_agg_mfma(
    const float* __restrict__ adj1, const float* __restrict__ adj2,
    const unsigned short* __restrict__ Ph, const unsigned short* __restrict__ Pl,
    const unsigned short* __restrict__ Pll, float* __restrict__ part) {
    // 2 buffers x 24 chunks (12 per k-step x 2 steps) x 1KB
    __shared__ __align__(16) unsigned short Bs[2][24][512];
    const int w = threadIdx.x >> 6, lane = threadIdx.x & 63;
    const int mt = blockIdx.x, ks = blockIdx.y, g = blockIdx.z;
    const float* __restrict__ A = g ? adj2 : adj1;
    const int l31 = lane & 31, lhi = lane >> 5;
    const float* Ap = A + (size_t)(mt * 128 + w * 32 + l31) * 4096 + ks * 512 + lhi * 8;

    // this wave stages chunks c = 3w .. 3w+2 (both k-steps of a pair)
    const unsigned short* src[3];
#pragma unroll
    for (int i = 0; i < 3; i++) {
        int c = w * 3 + i;
        const unsigned short* Pb = (c < 4) ? Ph : ((c < 8) ? Pl : Pll);
        src[i] = Pb + ((((size_t)(g * 256 + ks * 32)) * 4 + (c & 3)) * 64 + lane) * 8;
    }

    f32x16 acc[4] = {};
    // A regs for current pair (2 k-steps x 8 floats per lane)
    float4 a0 = *(const float4*)Ap,        a1 = *(const float4*)(Ap + 4);
    float4 a2 = *(const float4*)(Ap + 16), a3 = *(const float4*)(Ap + 20);

    // prologue: stage pair 0 into buffer 0 (full-drain barrier once is fine)
    {
        bf16x8 r0 = *(const bf16x8*)(src[0]);
        bf16x8 r1 = *(const bf16x8*)(src[1]);
        bf16x8 r2 = *(const bf16x8*)(src[2]);
        bf16x8 r3 = *(const bf16x8*)(src[0] + 2048);
        bf16x8 r4 = *(const bf16x8*)(src[1] + 2048);
        bf16x8 r5 = *(const bf16x8*)(src[2] + 2048);
        *(bf16x8*)&Bs[0][w * 3 + 0][lane * 8] = r0;
        *(bf16x8*)&Bs[0][w * 3 + 1][lane * 8] = r1;
        *(bf16x8*)&Bs[0][w * 3 + 2][lane * 8] = r2;
        *(bf16x8*)&Bs[0][12 + w * 3 + 0][lane * 8] = r3;
        *(bf16x8*)&Bs[0][12 + w * 3 + 1][lane * 8] = r4;
        *(bf16x8*)&Bs[0][12 + w * 3 + 2][lane * 8] = r5;
    }
    __syncthreads();

    for (int p = 0; p < 16; p++) {
        const int cur = p & 1;
        const bool more = (p + 1 < 16);
        // 1. issue global loads for pair p+1 (stay in flight across compute)
        bf16x8 r0, r1, r2, r3, r4, r5;
        if (more) {
            size_t adv = (size_t)(2 * (p + 1)) * 2048;
            r0 = *(const bf16x8*)(src[0] + adv);
            r1 = *(const bf16x8*)(src[1] + adv);
            r2 = *(const bf16x8*)(src[2] + adv);
            r3 = *(const bf16x8*)(src[0] + adv + 2048);
            r4 = *(const bf16x8*)(src[1] + adv + 2048);
            r5 = *(const bf16x8*)(src[2] + adv + 2048);
        }
        // A prefetch for next pair (crosses the raw barrier)
        const float* An = more ? (Ap + 32) : Ap;
        float4 n0 = *(const float4*)An,        n1 = *(const float4*)(An + 4);
        float4 n2 = *(const float4*)(An + 16), n3 = *(const float4*)(An + 20);
        Ap += 32;
        // 2+3. compute both k-steps of this pair
        step16(Bs[cur], 0,  lane, a0, a1, acc);
        step16(Bs[cur], 12, lane, a2, a3, acc);
        // 4. write staged regs into the other buffer
        if (more) {
            const int nb = cur ^ 1;
            *(bf16x8*)&Bs[nb][w * 3 + 0][lane * 8] = r0;
            *(bf16x8*)&Bs[nb][w * 3 + 1][lane * 8] = r1;
            *(bf16x8*)&Bs[nb][w * 3 + 2][lane * 8] = r2;
            *(bf16x8*)&Bs[nb][12 + w * 3 + 0][lane * 8] = r3;
            *(bf16x8*)&Bs[nb][12 + w * 3 + 1][lane * 8] = r4;
            *(bf16x8*)&Bs[nb][12 + w * 3 + 2][lane * 8] = r5;
        }
        // RAW barrier: lgkmcnt(0) publishes ds_writes; vmcnt NOT drained.
        asm volatile("s_waitcnt lgkmcnt(0)" ::: "memory");
        __builtin_amdgcn_sched_barrier(0);
        __builtin_amdgcn_s_barrier();
        a0 = n0; a1 = n1; a2 = n2; a3 = n3;
    }

    float* P = part + ((size_t)(g * 8 + ks) * 4096) * 128;
    const int rb = mt * 128 + w * 32 + 4 * lhi;
#pragma unroll
    for (int ct = 0; ct < 4; ct++) {
        const int c = ct * 32 + l31;
#pragma unroll
        for (int q = 0; q < 16; q++) {
            int r = rb + (q & 3) + 8 * (q >> 2);
            P[(size_t)r * 128 + c] = acc[ct][q];
        }
    }
}

// ---------------- reduce partials + self-loop + dinv, then postagg chain -> h ----------
__global__ __launch_bounds__(256) void k_reduce(const float* __restrict__ part,
                                                const float* __restrict__ tp,
                                                const float* __restrict__ dinv,
                                                float* __restrict__ h) {
    int wid = threadIdx.x >> 6, lane = threadIdx.x & 63;
    int row = blockIdx.x * 4 + wid;          // 0..8191
    int g = row >> 12, rr = row & 4095;
    float sx = 0.f, sy = 0.f;
    const float* P = part + ((size_t)(g * 8) * 4096 + rr) * 128;
#pragma unroll
    for (int ks = 0; ks < 8; ks++) {
        float2 v = ((const float2*)(P + (size_t)ks * 4096 * 128))[lane];
        sx += v.x; sy += v.y;
    }
    float2 tv = ((const float2*)(tp + (size_t)row * 128))[lane];
    float d = dinv[row];
    float vx = d * (sx + 10.0f * tv.x);
    float vy = d * (sy + 10.0f * tv.y);
    float n = fmaxf(sqrtf(wsum(vx * vx + vy * vy)), MIN_NORM);
    float e = tanhf(n) / n;
    float px = e * vx, py = e * vy;
    float nm = fmaxf(sqrtf(wsum(px * px + py * py)), MIN_NORM);
    if (nm > MAXN) { float s = MAXN / nm; px *= s; py *= s; }
    float nm2 = fmaxf(sqrtf(wsum(px * px + py * py)), MIN_NORM);
    float lsc = artanh_f(nm2) / nm2;
    float tx2 = fmaxf(lsc * px, 0.0f), ty2 = fmaxf(lsc * py, 0.0f);
    float nr = fmaxf(sqrtf(wsum(tx2 * tx2 + ty2 * ty2)), MIN_NORM);
    float e2 = tanhf(nr) / nr;
    float hx = e2 * tx2, hy = e2 * ty2;
    float nh = fmaxf(sqrtf(wsum(hx * hx + hy * hy)), MIN_NORM);
    if (nh > MAXN) { float s = MAXN / nh; hx *= s; hy *= s; }
    ((float2*)(h + (size_t)row * 128))[lane] = make_float2(hx, hy);
}

// ---------------- readout partials: per 128-row chunk, per column sum & max ----------------
__global__ __launch_bounds__(256) void k_red_part(const float* __restrict__ h,
                                                  float* __restrict__ part) {
    int chunk = blockIdx.x;                // 64 chunks x 128 rows
    int col = threadIdx.x & 127, half = threadIdx.x >> 7;
    float s = 0.f, m = -INFINITY;
    for (int i = 0; i < 64; i++) {
        int r = chunk * 128 + half * 64 + i;
        float v = h[(size_t)r * 128 + col];
        s += v;
        m = fmaxf(m, v);
    }
    __shared__ float ss[128], sm[128];
    if (half) { ss[col] = s; sm[col] = m; }
    __syncthreads();
    if (!half) {
        s += ss[col];
        m = fmaxf(m, sm[col]);
        part[(chunk * 2 + 0) * 128 + col] = s;
        part[(chunk * 2 + 1) * 128 + col] = m;
    }
}

__global__ void k_red_final(const float* __restrict__ part, float* __restrict__ feat) {
    int g = blockIdx.x, col = threadIdx.x;   // 128 threads
    float s = 0.f, m = -INFINITY;
    for (int c = g * 32; c < g * 32 + 32; c++) {
        s += part[(c * 2 + 0) * 128 + col];
        m = fmaxf(m, part[(c * 2 + 1) * 128 + col]);
    }
    feat[g * 256 + col] = s * (1.0f / 4096.0f);
    feat[g * 256 + 128 + col] = m;
}

// ---------------- MLP (128 blocks: one output neuron per block) ----------------
__global__ __launch_bounds__(256) void k_mlp_hidden(const float* __restrict__ feat,
                                                    const float* __restrict__ W1,
                                                    const float* __restrict__ b1,
                                                    float* __restrict__ hidden) {
    int j = blockIdx.x;      // 128
    int t = threadIdx.x;     // 256
    float p = 0.f;
    for (int k = t; k < 768; k += 256) {
        float f = (k < 512) ? feat[k] : (feat[k - 512] - feat[k - 256]);
        p = fmaf(f, W1[j * 768 + k], p);
    }
    p = wsum(p);
    __shared__ float ps[4];
    if ((t & 63) == 0) ps[t >> 6] = p;
    __syncthreads();
    if (t == 0) {
        float x = ps[0] + ps[1] + ps[2] + ps[3] + b1[j];
        hidden[j] = 0.5f * x * (1.0f + erff(x * 0.70710678118654752f));
    }
}

__global__ void k_mlp_out(const float* __restrict__ hidden, const float* __restrict__ W2,
                          const float* __restrict__ b2, float* __restrict__ out) {
    int t = threadIdx.x;   // 128
    float v = hidden[t] * W2[t];
    v = wsum(v);
    __shared__ float ps[2];
    if ((t & 63) == 0) ps[t >> 6] = v;
    __syncthreads();
    if (t == 0) out[0] = ps[0] + ps[1] + b2[0];
}

extern "C" void kernel_launch(void* const* d_in, const int* in_sizes, int n_in,
                              void* d_out, int out_size, void* d_ws, size_t ws_size,
                              hipStream_t stream) {
    (void)in_sizes; (void)n_in; (void)out_size; (void)ws_size;
    const float* x1 = (const float*)d_in[0];
    const float* x2 = (const float*)d_in[1];
    const float* adj1 = (const float*)d_in[2];
    const float* adj2 = (const float*)d_in[3];
    const float* W_stack = (const float*)d_in[6];
    const float* b_stack = (const float*)d_in[7];
    const float* W1 = (const float*)d_in[8];
    const float* b1 = (const float*)d_in[9];
    const float* W2 = (const float*)d_in[10];
    const float* b2 = (const float*)d_in[11];

    float* ws = (float*)d_ws;
    float* dinv = ws;                        // 8192
    float* hb   = ws + 8192;                 // 256
    float* Wt   = ws + 8448;                 // 32768
    float* h    = ws + 41216;                // 1048576
    float* mx   = h + 1048576;               // 1048576
    float* tp   = mx + 1048576;              // 1048576
    float* part = tp + 1048576;              // 2*8*4096*128 = 8388608
    float* rpart = part + 8388608;           // 16384
    float* feat = rpart + 16384;             // 512
    float* hid  = feat + 512;                // 128
    unsigned short* Ph  = (unsigned short*)(hid + 128);   // 2*128*4096 each
    unsigned short* Pl  = Ph + 2 * 128 * 4096;
    unsigned short* Pll = Pl + 2 * 128 * 4096;

    k_transW_hb<<<dim3(64, 2), 256, 0, stream>>>(W_stack, Wt, b_stack, hb);
    k_deg<<<dim3(4096, 2), 256, 0, stream>>>(adj1, adj2, dinv);
    k_manifold<<<2048, 256, 0, stream>>>(x1, x2, h);
    for (int l = 0; l < 2; l++) {
        k_lin<<<128, 256, 0, stream>>>(h, Wt + l * 16384, mx);
        k_postlin<<<2048, 256, 0, stream>>>(h, mx, hb + l * 128, dinv, tp);
        k_tsplit<<<dim3(64, 2), 256, 0, stream>>>(tp, Ph, Pl, Pll);
        k_agg_mfma<<<dim3(32, 8, 2), 256, 0, stream>>>(adj1, adj2, Ph, Pl, Pll, part);
        k_reduce<<<2048, 256, 0, stream>>>(part, tp, dinv, h);
    }
    k_red_part<<<64, 256, 0, stream>>>(h, rpart);
    k_red_final<<<2, 128, 0, stream>>>(rpart, feat);
    k_mlp_hidden<<<128, 256, 0, stream>>>(feat, W1, b1, hid);
    k_mlp_out<<<1, 128, 0, stream>>>(hid, W2, b2, (float*)d_out);
}